// Round 2
// baseline (596.044 us; speedup 1.0000x reference)
//
#include <hip/hip_runtime.h>

#define NREL 3
// capacity bounds for the pruned dependence cone (expected ~45K/15K/30K/10K;
// caps are 3-6x expected; all pushes are bounds-checked so overflow cannot fault)
#define CAP0 131072   // nodes needing h0
#define CAP1 65536    // nodes needing h1
#define CAPE1 262144  // layer-1 relevant edges
#define CAPE2 65536   // layer-2 relevant edges

// ctr indices: 0 = n1 count, 1 = n0 count, 2 = e1 count, 3 = e2 count

// ---- mark last node of each graph: inv_map[last]=g, mask1[last]=1 ----
__global__ void mark_last_k(const int* __restrict__ ptr, int* __restrict__ inv_map,
                            int* __restrict__ mask1, int G) {
    int g = blockIdx.x * blockDim.x + threadIdx.x;
    if (g >= G) return;
    int last = ptr[g + 1] - 1;
    inv_map[last] = g;
    mask1[last] = 1;
}

// ---- pass over edges: edges into last nodes -> elist2; their srcs need h1 ----
__global__ void edge_pass1_k(const int* __restrict__ src, const int* __restrict__ dst,
                             const int* __restrict__ inv_map, int* __restrict__ mask1,
                             int* __restrict__ elist2, int* __restrict__ ctr, int nE) {
    int e = blockIdx.x * blockDim.x + threadIdx.x;
    if (e >= nE) return;
    if (inv_map[dst[e]] >= 0) {
        mask1[src[e]] = 1;
        int p = atomicAdd(&ctr[3], 1);
        if (p < CAPE2) elist2[p] = e;
    }
}

// ---- compact need1 -> slot1 / nodes1 ----
__global__ void compact1_k(const int* __restrict__ mask1, int* __restrict__ slot1,
                           int* __restrict__ nodes1, int* __restrict__ ctr, int nN) {
    int n = blockIdx.x * blockDim.x + threadIdx.x;
    if (n >= nN) return;
    int s = -1;
    if (mask1[n]) {
        int p = atomicAdd(&ctr[0], 1);
        if (p < CAP1) { s = p; nodes1[p] = n; }
    }
    slot1[n] = s;
}

// ---- pass over edges: edges into need1 -> elist1, counts, srcs need h0 ----
__global__ void edge_pass2_k(const int* __restrict__ src, const int* __restrict__ dst,
                             const int* __restrict__ et, const int* __restrict__ slot1,
                             int* __restrict__ mask0, int* __restrict__ elist1,
                             float* __restrict__ cntc, int* __restrict__ ctr, int nE) {
    int e = blockIdx.x * blockDim.x + threadIdx.x;
    if (e >= nE) return;
    int s1 = slot1[dst[e]];
    if (s1 >= 0) {
        mask0[src[e]] = 1;
        atomicAdd(&cntc[s1 * 4 + et[e]], 1.0f);
        int p = atomicAdd(&ctr[2], 1);
        if (p < CAPE1) elist1[p] = e;
    }
}

// ---- compact need0 (mask0 OR need1) -> slot0 / nodes0 ----
__global__ void compact0_k(const int* __restrict__ mask0, const int* __restrict__ mask1,
                           int* __restrict__ slot0, int* __restrict__ nodes0,
                           int* __restrict__ ctr, int nN) {
    int n = blockIdx.x * blockDim.x + threadIdx.x;
    if (n >= nN) return;
    int s = -1;
    if (mask0[n] || mask1[n]) {
        int p = atomicAdd(&ctr[1], 1);
        if (p < CAP0) { s = p; nodes0[p] = n; }
    }
    slot0[n] = s;
}

// ---- counts -> reciprocals (mean folded into per-edge scale) ----
__global__ void inv_k(float* __restrict__ cntc, int n) {
    int i = blockIdx.x * blockDim.x + threadIdx.x;
    if (i < n) cntc[i] = 1.0f / fmaxf(cntc[i], 1.0f);
}

// ---- embed + pre-linear + relu, only for nodes0 cone ----
__global__ void h0_k(const int* __restrict__ x, const float* __restrict__ se,
                     const float* __restrict__ ce, const float* __restrict__ pw,
                     const float* __restrict__ pb, const int* __restrict__ nodes0,
                     const int* __restrict__ ctr, float* __restrict__ h0c) {
    __shared__ float s_se[128], s_ce[128], s_pw[512], s_pb[32];
    int t = threadIdx.x;
    if (t < 128) { s_se[t] = se[t]; s_ce[t] = ce[t]; }
    if (t < 32)  s_pb[t] = pb[t];
    for (int i = t; i < 512; i += 256) s_pw[i] = pw[i];
    __syncthreads();
    int c0 = min(ctr[1], CAP0);
    int total = c0 * 32;
    for (int idx = blockIdx.x * blockDim.x + t; idx < total; idx += gridDim.x * blockDim.x) {
        int i = idx >> 5, f = idx & 31;
        int n = nodes0[i];
        int x0 = x[n * 2], x1 = x[n * 2 + 1];
        float acc = s_pb[f];
#pragma unroll
        for (int k = 0; k < 8; k++) acc += s_se[x0 * 8 + k] * s_pw[k * 32 + f];
#pragma unroll
        for (int k = 0; k < 8; k++) acc += s_ce[x1 * 8 + k] * s_pw[(k + 8) * 32 + f];
        h0c[i * 32 + f] = fmaxf(acc, 0.0f);
    }
}

// ---- layer-1 messages over elist1: wave per edge, lane = out feature ----
__global__ void msg1_k(const int* __restrict__ src, const int* __restrict__ dst,
                       const int* __restrict__ et, const int* __restrict__ elist1,
                       const int* __restrict__ slot0, const int* __restrict__ slot1,
                       const float* __restrict__ w1r, const float* __restrict__ cinv,
                       const float* __restrict__ h0c, float* __restrict__ agg1,
                       const int* __restrict__ ctr) {
    __shared__ float s_w[NREL * 32 * 64];   // 24 KB
    int t = threadIdx.x;
    for (int i = t; i < NREL * 32 * 64; i += blockDim.x) s_w[i] = w1r[i];
    __syncthreads();
    int ec = min(ctr[2], CAPE1);
    int f = t & 63;
    int wv  = (blockIdx.x * blockDim.x + t) >> 6;
    int nwv = (gridDim.x * blockDim.x) >> 6;
    for (int j = wv; j < ec; j += nwv) {
        int e = elist1[j];
        int s = src[e], d = dst[e], r = et[e];
        int s0 = slot0[s], s1 = slot1[d];
        if (s0 < 0 || s1 < 0) continue;
        float scale = cinv[s1 * 4 + r];
        const float4* h4 = (const float4*)(h0c + (size_t)s0 * 32);
        float acc = 0.0f;
#pragma unroll
        for (int k4 = 0; k4 < 8; k4++) {
            float4 hv = h4[k4];
            const float* wp = &s_w[r * 2048 + (k4 * 4) * 64 + f];
            acc += hv.x * wp[0] + hv.y * wp[64] + hv.z * wp[128] + hv.w * wp[192];
        }
        atomicAdd(&agg1[(size_t)s1 * 64 + f], acc * scale);
    }
}

// ---- finalize layer 1: h1 = relu(agg1 + h0 @ w_root + b) over nodes1 ----
__global__ void fin1_k(const float* __restrict__ wroot, const float* __restrict__ b,
                       const int* __restrict__ nodes1, const int* __restrict__ slot0,
                       const float* __restrict__ h0c, const float* __restrict__ agg1,
                       float* __restrict__ h1c, const int* __restrict__ ctr) {
    __shared__ float s_wr[32 * 64], s_b[64];
    int t = threadIdx.x;
    for (int i = t; i < 32 * 64; i += blockDim.x) s_wr[i] = wroot[i];
    if (t < 64) s_b[t] = b[t];
    __syncthreads();
    int c1 = min(ctr[0], CAP1);
    int f = t & 63;
    int wv  = (blockIdx.x * blockDim.x + t) >> 6;
    int nwv = (gridDim.x * blockDim.x) >> 6;
    for (int j = wv; j < c1; j += nwv) {
        int n = nodes1[j];
        int s0 = slot0[n];
        float acc = s_b[f];
        const float4* h4 = (const float4*)(h0c + (size_t)s0 * 32);
#pragma unroll
        for (int k4 = 0; k4 < 8; k4++) {
            float4 hv = h4[k4];
            const float* wp = &s_wr[(k4 * 4) * 64 + f];
            acc += hv.x * wp[0] + hv.y * wp[64] + hv.z * wp[128] + hv.w * wp[192];
        }
        h1c[(size_t)j * 64 + f] = fmaxf(agg1[(size_t)j * 64 + f] + acc, 0.0f);
    }
}

// ---- layer-2 messages over elist2 into per-graph agg2 ----
__global__ void msg2_k(const int* __restrict__ src, const int* __restrict__ dst,
                       const int* __restrict__ et, const int* __restrict__ elist2,
                       const int* __restrict__ slot1, const int* __restrict__ inv_map,
                       const float* __restrict__ w2r, const float* __restrict__ cinv,
                       const float* __restrict__ h1c, float* __restrict__ agg2,
                       const int* __restrict__ ctr) {
    __shared__ float s_w[NREL * 64 * 64];   // 48 KB
    int t = threadIdx.x;
    for (int i = t; i < NREL * 64 * 64; i += blockDim.x) s_w[i] = w2r[i];
    __syncthreads();
    int ec = min(ctr[3], CAPE2);
    int f = t & 63;
    int wv  = (blockIdx.x * blockDim.x + t) >> 6;
    int nwv = (gridDim.x * blockDim.x) >> 6;
    for (int j = wv; j < ec; j += nwv) {
        int e = elist2[j];
        int s = src[e], d = dst[e], r = et[e];
        int ss = slot1[s], sd = slot1[d], g = inv_map[d];
        if (ss < 0 || sd < 0 || g < 0) continue;
        float scale = cinv[sd * 4 + r];
        const float4* h4 = (const float4*)(h1c + (size_t)ss * 64);
        float acc = 0.0f;
#pragma unroll
        for (int k4 = 0; k4 < 16; k4++) {
            float4 hv = h4[k4];
            const float* wp = &s_w[r * 4096 + (k4 * 4) * 64 + f];
            acc += hv.x * wp[0] + hv.y * wp[64] + hv.z * wp[128] + hv.w * wp[192];
        }
        atomicAdd(&agg2[(size_t)g * 64 + f], acc * scale);
    }
}

// ---- finalize layer 2 + classifier, fused: wave per graph ----
__global__ void fin2cls_k(const int* __restrict__ ptr, const int* __restrict__ slot1,
                          const float* __restrict__ wroot, const float* __restrict__ b2,
                          const float* __restrict__ cw, const float* __restrict__ cb,
                          const float* __restrict__ h1c, const float* __restrict__ agg2,
                          float* __restrict__ out, int G) {
    __shared__ float s_wr[64 * 64], s_cw[64 * 10], s_cb[10], s_b[64], s_h2[256];
    int t = threadIdx.x;
    for (int i = t; i < 64 * 64; i += blockDim.x) s_wr[i] = wroot[i];
    for (int i = t; i < 640; i += blockDim.x) s_cw[i] = cw[i];
    if (t < 10) s_cb[t] = cb[t];
    if (t < 64) s_b[t] = b2[t];
    __syncthreads();
    int wvl = t >> 6, f = t & 63;
    int g = blockIdx.x * 4 + wvl;
    if (g < G) {
        int last = ptr[g + 1] - 1;
        int s1 = slot1[last];
        float acc = s_b[f];
        const float4* h4 = (const float4*)(h1c + (size_t)s1 * 64);
#pragma unroll
        for (int k4 = 0; k4 < 16; k4++) {
            float4 hv = h4[k4];
            const float* wp = &s_wr[(k4 * 4) * 64 + f];
            acc += hv.x * wp[0] + hv.y * wp[64] + hv.z * wp[128] + hv.w * wp[192];
        }
        s_h2[wvl * 64 + f] = fmaxf(agg2[(size_t)g * 64 + f] + acc, 0.0f);
    }
    __syncthreads();
    if (g < G && f < 10) {
        float acc = s_cb[f];
#pragma unroll
        for (int k = 0; k < 64; k++) acc += s_h2[wvl * 64 + k] * s_cw[k * 10 + f];
        out[g * 10 + f] = acc;
    }
}

static inline size_t rnd(size_t x) { return (x + 255) & ~(size_t)255; }

extern "C" void kernel_launch(void* const* d_in, const int* in_sizes, int n_in,
                              void* d_out, int out_size, void* d_ws, size_t ws_size,
                              hipStream_t stream) {
    const int*   x    = (const int*)d_in[0];
    const int*   ei   = (const int*)d_in[1];
    const int*   et   = (const int*)d_in[2];
    const int*   ptr  = (const int*)d_in[3];
    const float* se   = (const float*)d_in[4];
    const float* ce   = (const float*)d_in[5];
    const float* pw   = (const float*)d_in[6];
    const float* pb   = (const float*)d_in[7];
    const float* w1r  = (const float*)d_in[8];
    const float* w1rt = (const float*)d_in[9];
    const float* b1   = (const float*)d_in[10];
    const float* w2r  = (const float*)d_in[11];
    const float* w2rt = (const float*)d_in[12];
    const float* b2   = (const float*)d_in[13];
    const float* cw   = (const float*)d_in[14];
    const float* cb   = (const float*)d_in[15];
    float* out = (float*)d_out;

    const int nN = in_sizes[0] / 2;   // 500000
    const int nE = in_sizes[2];       // 1000000
    const int G  = in_sizes[3] - 1;   // 5000

    const int* src = ei;
    const int* dst = ei + nE;

    // ---- workspace layout (zero-region first, then 0xFF region, then uninit) ----
    char* p = (char*)d_ws;
    size_t off = 0;
    auto take = [&](size_t bytes) { size_t o = off; off += rnd(bytes); return o; };

    int*   ctr    = (int*)  (p + take(4 * sizeof(int)));
    int*   mask1  = (int*)  (p + take((size_t)nN * 4));
    int*   mask0  = (int*)  (p + take((size_t)nN * 4));
    float* cntc   = (float*)(p + take((size_t)CAP1 * 4 * 4));
    float* agg1   = (float*)(p + take((size_t)CAP1 * 64 * 4));
    float* agg2   = (float*)(p + take((size_t)G * 64 * 4));
    size_t zero_bytes = off;
    int*   inv_map = (int*) (p + take((size_t)nN * 4));
    size_t ff_off = zero_bytes, ff_bytes = off - zero_bytes;
    int*   slot1  = (int*)  (p + take((size_t)nN * 4));
    int*   slot0  = (int*)  (p + take((size_t)nN * 4));
    int*   elist1 = (int*)  (p + take((size_t)CAPE1 * 4));
    int*   elist2 = (int*)  (p + take((size_t)CAPE2 * 4));
    int*   nodes1 = (int*)  (p + take((size_t)CAP1 * 4));
    int*   nodes0 = (int*)  (p + take((size_t)CAP0 * 4));
    float* h0c    = (float*)(p + take((size_t)CAP0 * 32 * 4));
    float* h1c    = (float*)(p + take((size_t)CAP1 * 64 * 4));
    // total ~65 MB — if ws_size is smaller than this we cannot run safely;
    // (void)ws_size; the harness workspace is assumed >= this footprint.

    hipMemsetAsync(p, 0, zero_bytes, stream);
    hipMemsetAsync(p + ff_off, 0xFF, ff_bytes, stream);   // inv_map = -1

    mark_last_k<<<(G + 255) / 256, 256, 0, stream>>>(ptr, inv_map, mask1, G);
    edge_pass1_k<<<(nE + 255) / 256, 256, 0, stream>>>(src, dst, inv_map, mask1, elist2, ctr, nE);
    compact1_k<<<(nN + 255) / 256, 256, 0, stream>>>(mask1, slot1, nodes1, ctr, nN);
    edge_pass2_k<<<(nE + 255) / 256, 256, 0, stream>>>(src, dst, et, slot1, mask0, elist1, cntc, ctr, nE);
    compact0_k<<<(nN + 255) / 256, 256, 0, stream>>>(mask0, mask1, slot0, nodes0, ctr, nN);
    inv_k<<<(CAP1 * 4 + 255) / 256, 256, 0, stream>>>(cntc, CAP1 * 4);
    h0_k<<<512, 256, 0, stream>>>(x, se, ce, pw, pb, nodes0, ctr, h0c);
    msg1_k<<<1024, 256, 0, stream>>>(src, dst, et, elist1, slot0, slot1, w1r, cntc, h0c, agg1, ctr);
    fin1_k<<<512, 256, 0, stream>>>(w1rt, b1, nodes1, slot0, h0c, agg1, h1c, ctr);
    msg2_k<<<512, 256, 0, stream>>>(src, dst, et, elist2, slot1, inv_map, w2r, cntc, h1c, agg2, ctr);
    fin2cls_k<<<(G + 3) / 4, 256, 0, stream>>>(ptr, slot1, w2rt, b2, cw, cb, h1c, agg2, out, G);
}